// Round 5
// baseline (451.734 us; speedup 1.0000x reference)
//
#include <hip/hip_runtime.h>
#include <math.h>

#define N_NODES 50000
#define N_EDGES 1600000
#define N_FEAT  256
#define N_HID   128
#define N_CLASS 64
#define SCAN_NBLK ((N_NODES + 1023) / 1024)
#define FIXSCALE 268435456.0f  // 2^28
#define EPB 2048               // edges per fused block

__device__ __forceinline__ unsigned short f2bf(float f) {
  unsigned int u = __float_as_uint(f);
  unsigned int r = (u + 0x7fffu + ((u >> 16) & 1u)) >> 16;  // RNE
  return (unsigned short)r;
}

// ---------------- fused: gemm1 (x@W1 -> bf16) + edge histogram/rank atomics ----------------
__global__ __launch_bounds__(256) void fused_gemm1_deg_kernel(
    const float* __restrict__ A, const float* __restrict__ B,
    unsigned short* __restrict__ C,
    const int* __restrict__ col, const float* __restrict__ ew,
    unsigned long long* __restrict__ packed, unsigned short* __restrict__ rank) {
  constexpr int BM = 64, BN = N_HID, BK = 64, K = N_FEAT;
  constexpr int TC = BN / 4, TR = 256 / TC, RM = BM / TR;
  __shared__ float As[BM][BK + 4];
  __shared__ float Bs[BK][BN];

  int t = threadIdx.x;

  // --- issue this block's edge atomics EARLY; hold returns in regs ---
  int ebase = blockIdx.x * EPB + t;
  unsigned long long old0 = 0, old1 = 0, old2 = 0, old3 = 0,
                     old4 = 0, old5 = 0, old6 = 0, old7 = 0;
#define EDGE_ATOMIC(i, dst)                                                      \
  {                                                                              \
    int e = ebase + (i) * 256;                                                   \
    if (e < N_EDGES) {                                                           \
      int c = col[e];                                                            \
      unsigned long long fix = (unsigned long long)__float2uint_rn(ew[e] * FIXSCALE); \
      dst = atomicAdd(&packed[c], (1ULL << 40) | fix);                           \
    }                                                                            \
  }
  EDGE_ATOMIC(0, old0) EDGE_ATOMIC(1, old1) EDGE_ATOMIC(2, old2) EDGE_ATOMIC(3, old3)
  EDGE_ATOMIC(4, old4) EDGE_ATOMIC(5, old5) EDGE_ATOMIC(6, old6) EDGE_ATOMIC(7, old7)
#undef EDGE_ATOMIC

  // --- gemm tile ---
  int m0 = blockIdx.x * BM;
  int tc = t % TC, tr = t / TC;
  float acc[RM][4];
#pragma unroll
  for (int r = 0; r < RM; ++r)
#pragma unroll
    for (int c = 0; c < 4; ++c) acc[r][c] = 0.f;

  for (int k0 = 0; k0 < K; k0 += BK) {
    constexpr int F4R = BK / 4;
#pragma unroll
    for (int p = 0; p < (BM * F4R) / 256; ++p) {
      int row = t / F4R + p * (256 / F4R);
      int c4  = t % F4R;
      int gr  = m0 + row;
      float4 v = make_float4(0.f, 0.f, 0.f, 0.f);
      if (gr < N_NODES) v = *(const float4*)&A[(size_t)gr * K + k0 + c4 * 4];
      *(float4*)&As[row][c4 * 4] = v;
    }
    constexpr int BF4 = BK * BN / 4;
#pragma unroll
    for (int p = 0; p < BF4 / 256; ++p) {
      int idx = p * 256 + t;
      int row = idx / (BN / 4), c4 = idx % (BN / 4);
      *(float4*)&Bs[row][c4 * 4] = *(const float4*)&B[(size_t)(k0 + row) * BN + c4 * 4];
    }
    __syncthreads();
    for (int kk = 0; kk < BK; kk += 4) {
      float4 b0 = *(const float4*)&Bs[kk + 0][tc * 4];
      float4 b1 = *(const float4*)&Bs[kk + 1][tc * 4];
      float4 b2 = *(const float4*)&Bs[kk + 2][tc * 4];
      float4 b3 = *(const float4*)&Bs[kk + 3][tc * 4];
#pragma unroll
      for (int r = 0; r < RM; ++r) {
        float4 a = *(const float4*)&As[tr * RM + r][kk];
        acc[r][0] = fmaf(a.x, b0.x, fmaf(a.y, b1.x, fmaf(a.z, b2.x, fmaf(a.w, b3.x, acc[r][0]))));
        acc[r][1] = fmaf(a.x, b0.y, fmaf(a.y, b1.y, fmaf(a.z, b2.y, fmaf(a.w, b3.y, acc[r][1]))));
        acc[r][2] = fmaf(a.x, b0.z, fmaf(a.y, b1.z, fmaf(a.z, b2.z, fmaf(a.w, b3.z, acc[r][2]))));
        acc[r][3] = fmaf(a.x, b0.w, fmaf(a.y, b1.w, fmaf(a.z, b2.w, fmaf(a.w, b3.w, acc[r][3]))));
      }
    }
    __syncthreads();
  }
#pragma unroll
  for (int r = 0; r < RM; ++r) {
    int gr = m0 + tr * RM + r;
    if (gr < N_NODES) {
      uint2 o;
      o.x = (unsigned int)f2bf(acc[r][0]) | ((unsigned int)f2bf(acc[r][1]) << 16);
      o.y = (unsigned int)f2bf(acc[r][2]) | ((unsigned int)f2bf(acc[r][3]) << 16);
      *(uint2*)&C[(size_t)gr * BN + tc * 4] = o;
    }
  }

  // --- write ranks (atomic returns have long since landed) ---
#define RANK_WRITE(i, src)                                                \
  {                                                                       \
    int e = ebase + (i) * 256;                                            \
    if (e < N_EDGES) rank[e] = (unsigned short)(src >> 40);               \
  }
  RANK_WRITE(0, old0) RANK_WRITE(1, old1) RANK_WRITE(2, old2) RANK_WRITE(3, old3)
  RANK_WRITE(4, old4) RANK_WRITE(5, old5) RANK_WRITE(6, old6) RANK_WRITE(7, old7)
#undef RANK_WRITE
}

// ---------------- scan1: unpack counts/dinv from packed + block-local exclusive scan ----
__global__ __launch_bounds__(256) void scan1_kernel(
    const unsigned long long* __restrict__ packed, int* __restrict__ rowptr,
    int* __restrict__ partials, float* __restrict__ dinv) {
  __shared__ int wsum[4];
  __shared__ int woff[4];
  int t = threadIdx.x, b = blockIdx.x;
  int base = b * 1024 + t * 4;
  int v0 = 0, v1 = 0, v2 = 0, v3 = 0;
#pragma unroll
  for (int j = 0; j < 4; ++j) {
    int i = base + j;
    if (i < N_NODES) {
      unsigned long long p = packed[i];
      int c = (int)(p >> 40);
      float deg = (float)(long long)(p & 0xFFFFFFFFFFULL) * (1.0f / FIXSCALE);
      dinv[i] = rsqrtf(deg + 1.0f);  // +1 = self-loop weight
      if (j == 0) v0 = c; else if (j == 1) v1 = c; else if (j == 2) v2 = c; else v3 = c;
    }
  }
  int s1 = v0 + v1, s2 = s1 + v2, s3 = s2 + v3;
  int lane = t & 63, w = t >> 6;
  int inc = s3;
#pragma unroll
  for (int off = 1; off < 64; off <<= 1) {
    int u = __shfl_up(inc, off, 64);
    if (lane >= off) inc += u;
  }
  if (lane == 63) wsum[w] = inc;
  __syncthreads();
  if (t == 0) {
    int a = 0;
#pragma unroll
    for (int i = 0; i < 4; ++i) { woff[i] = a; a += wsum[i]; }
    partials[b] = a;
  }
  __syncthreads();
  int ex = woff[w] + inc - s3;
  if (base + 0 < N_NODES) rowptr[base + 0] = ex;
  if (base + 1 < N_NODES) rowptr[base + 1] = ex + v0;
  if (base + 2 < N_NODES) rowptr[base + 2] = ex + s1;
  if (base + 3 < N_NODES) rowptr[base + 3] = ex + s2;
}

__global__ void scan2_kernel(int* __restrict__ partials, int* __restrict__ rowptr) {
  if (threadIdx.x == 0 && blockIdx.x == 0) {
    int a = 0;
    for (int i = 0; i < SCAN_NBLK; ++i) { int x = partials[i]; partials[i] = a; a += x; }
    rowptr[N_NODES] = a;  // == N_EDGES
  }
}

__global__ __launch_bounds__(256) void scan3_kernel(
    int* __restrict__ rowptr, const int* __restrict__ partials) {
  int i = blockIdx.x * 256 + threadIdx.x;
  if (i < N_NODES) rowptr[i] += partials[i >> 10];
}

// ---------------- atomic-free scatter into CSC ----------------
__global__ __launch_bounds__(256) void scatter_kernel(
    const int* __restrict__ row, const int* __restrict__ col,
    const float* __restrict__ ew, const unsigned short* __restrict__ rank,
    const float* __restrict__ dinv, const int* __restrict__ rowptr,
    int2* __restrict__ ep, int E) {
  int e = blockIdx.x * 256 + threadIdx.x;
  if (e >= E) return;
  int r = row[e], c = col[e];
  float w = dinv[r] * ew[e] * dinv[c];
  int pos = rowptr[c] + (int)rank[e];
  ep[pos] = make_int2(r, __float_as_int(w));
}

// ---------------- standalone fp32 GEMM, bf16 out (layer 2) ----------------
template <int BN, int BK, int K>
__global__ __launch_bounds__(256) void gemm_kernel(
    const float* __restrict__ A, const float* __restrict__ B,
    unsigned short* __restrict__ C, int M) {
  constexpr int BM = 64;
  constexpr int TC = BN / 4;
  constexpr int TR = 256 / TC;
  constexpr int RM = BM / TR;
  __shared__ float As[BM][BK + 4];
  __shared__ float Bs[BK][BN];

  int t  = threadIdx.x;
  int m0 = blockIdx.x * BM;
  int tc = t % TC, tr = t / TC;

  float acc[RM][4];
#pragma unroll
  for (int r = 0; r < RM; ++r)
#pragma unroll
    for (int c = 0; c < 4; ++c) acc[r][c] = 0.f;

  for (int k0 = 0; k0 < K; k0 += BK) {
    constexpr int F4R = BK / 4;
#pragma unroll
    for (int p = 0; p < (BM * F4R) / 256; ++p) {
      int row = t / F4R + p * (256 / F4R);
      int c4  = t % F4R;
      int gr  = m0 + row;
      float4 v = make_float4(0.f, 0.f, 0.f, 0.f);
      if (gr < M) v = *(const float4*)&A[(size_t)gr * K + k0 + c4 * 4];
      *(float4*)&As[row][c4 * 4] = v;
    }
    constexpr int BF4 = BK * BN / 4;
#pragma unroll
    for (int p = 0; p < BF4 / 256; ++p) {
      int idx = p * 256 + t;
      int row = idx / (BN / 4), c4 = idx % (BN / 4);
      *(float4*)&Bs[row][c4 * 4] = *(const float4*)&B[(size_t)(k0 + row) * BN + c4 * 4];
    }
    __syncthreads();

    for (int kk = 0; kk < BK; kk += 4) {
      float4 b0 = *(const float4*)&Bs[kk + 0][tc * 4];
      float4 b1 = *(const float4*)&Bs[kk + 1][tc * 4];
      float4 b2 = *(const float4*)&Bs[kk + 2][tc * 4];
      float4 b3 = *(const float4*)&Bs[kk + 3][tc * 4];
#pragma unroll
      for (int r = 0; r < RM; ++r) {
        float4 a = *(const float4*)&As[tr * RM + r][kk];
        acc[r][0] = fmaf(a.x, b0.x, fmaf(a.y, b1.x, fmaf(a.z, b2.x, fmaf(a.w, b3.x, acc[r][0]))));
        acc[r][1] = fmaf(a.x, b0.y, fmaf(a.y, b1.y, fmaf(a.z, b2.y, fmaf(a.w, b3.y, acc[r][1]))));
        acc[r][2] = fmaf(a.x, b0.z, fmaf(a.y, b1.z, fmaf(a.z, b2.z, fmaf(a.w, b3.z, acc[r][2]))));
        acc[r][3] = fmaf(a.x, b0.w, fmaf(a.y, b1.w, fmaf(a.z, b2.w, fmaf(a.w, b3.w, acc[r][3]))));
      }
    }
    __syncthreads();
  }
#pragma unroll
  for (int r = 0; r < RM; ++r) {
    int gr = m0 + tr * RM + r;
    if (gr < M) {
      uint2 o;
      o.x = (unsigned int)f2bf(acc[r][0]) | ((unsigned int)f2bf(acc[r][1]) << 16);
      o.y = (unsigned int)f2bf(acc[r][2]) | ((unsigned int)f2bf(acc[r][3]) << 16);
      *(uint2*)&C[(size_t)gr * BN + tc * 4] = o;
    }
  }
}

// ---------------- aggregation D=128 ----------------
__global__ __launch_bounds__(256) void agg128_kernel(
    const unsigned short* __restrict__ h, const int* __restrict__ rowptr,
    const int2* __restrict__ ep, const float* __restrict__ dinv,
    const float* __restrict__ bias, float* __restrict__ out, int n) {
  int wid  = (int)((blockIdx.x * 256 + threadIdx.x) >> 6);
  int lane = threadIdx.x & 63;
  if (wid >= n) return;
  int s = rowptr[wid], e_end = rowptr[wid + 1];
  unsigned int f2 = 2u * lane;
  float a0 = 0.f, a1 = 0.f, b0 = 0.f, b1 = 0.f;
  int e = s;
  for (; e + 1 < e_end; e += 2) {
    int2 p0 = ep[e], p1 = ep[e + 1];
    unsigned int h0 = *(const unsigned int*)(h + ((size_t)p0.x << 7) + f2);
    unsigned int h1 = *(const unsigned int*)(h + ((size_t)p1.x << 7) + f2);
    float w0 = __int_as_float(p0.y), w1 = __int_as_float(p1.y);
    a0 = fmaf(w0, __uint_as_float(h0 << 16), a0);
    a1 = fmaf(w0, __uint_as_float(h0 & 0xffff0000u), a1);
    b0 = fmaf(w1, __uint_as_float(h1 << 16), b0);
    b1 = fmaf(w1, __uint_as_float(h1 & 0xffff0000u), b1);
  }
  if (e < e_end) {
    int2 p0 = ep[e];
    unsigned int h0 = *(const unsigned int*)(h + ((size_t)p0.x << 7) + f2);
    float w0 = __int_as_float(p0.y);
    a0 = fmaf(w0, __uint_as_float(h0 << 16), a0);
    a1 = fmaf(w0, __uint_as_float(h0 & 0xffff0000u), a1);
  }
  float di = dinv[wid], sw = di * di;
  unsigned int hs = *(const unsigned int*)(h + ((size_t)wid << 7) + f2);
  a0 = fmaf(sw, __uint_as_float(hs << 16), a0);
  a1 = fmaf(sw, __uint_as_float(hs & 0xffff0000u), a1);
  float v0 = a0 + b0 + bias[f2];
  float v1 = a1 + b1 + bias[f2 + 1];
  v0 = 1.f / (1.f + expf(-v0));
  v1 = 1.f / (1.f + expf(-v1));
  *(float2*)&out[((size_t)wid << 7) + f2] = make_float2(v0, v1);
}

// ---------------- aggregation D=64 ----------------
__global__ __launch_bounds__(256) void agg64_kernel(
    const unsigned short* __restrict__ h, const int* __restrict__ rowptr,
    const int2* __restrict__ ep, const float* __restrict__ dinv,
    const float* __restrict__ bias, float* __restrict__ out, int n) {
  int wid  = (int)((blockIdx.x * 256 + threadIdx.x) >> 6);
  int lane = threadIdx.x & 63;
  if (wid >= n) return;
  int half = lane >> 5, ll = lane & 31;
  unsigned int f2 = 2u * ll;
  int s = rowptr[wid], e_end = rowptr[wid + 1];
  float a0 = 0.f, a1 = 0.f, b0 = 0.f, b1 = 0.f;
  int e = s + half;
  for (; e + 2 < e_end; e += 4) {
    int2 p0 = ep[e], p1 = ep[e + 2];
    unsigned int h0 = *(const unsigned int*)(h + ((size_t)p0.x << 6) + f2);
    unsigned int h1 = *(const unsigned int*)(h + ((size_t)p1.x << 6) + f2);
    float w0 = __int_as_float(p0.y), w1 = __int_as_float(p1.y);
    a0 = fmaf(w0, __uint_as_float(h0 << 16), a0);
    a1 = fmaf(w0, __uint_as_float(h0 & 0xffff0000u), a1);
    b0 = fmaf(w1, __uint_as_float(h1 << 16), b0);
    b1 = fmaf(w1, __uint_as_float(h1 & 0xffff0000u), b1);
  }
  if (e < e_end) {
    int2 p0 = ep[e];
    unsigned int h0 = *(const unsigned int*)(h + ((size_t)p0.x << 6) + f2);
    float w0 = __int_as_float(p0.y);
    a0 = fmaf(w0, __uint_as_float(h0 << 16), a0);
    a1 = fmaf(w0, __uint_as_float(h0 & 0xffff0000u), a1);
  }
  a0 += b0; a1 += b1;
  if (half == 0) {
    float di = dinv[wid], sw = di * di;
    unsigned int hs = *(const unsigned int*)(h + ((size_t)wid << 6) + f2);
    a0 = fmaf(sw, __uint_as_float(hs << 16), a0);
    a1 = fmaf(sw, __uint_as_float(hs & 0xffff0000u), a1);
  }
  a0 += __shfl_xor(a0, 32, 64);
  a1 += __shfl_xor(a1, 32, 64);
  if (half == 0) {
    float v0 = tanhf(a0 + bias[f2]);
    float v1 = tanhf(a1 + bias[f2 + 1]);
    *(float2*)&out[(size_t)wid * 64 + f2] = make_float2(v0, v1);
  }
}

extern "C" void kernel_launch(void* const* d_in, const int* in_sizes, int n_in,
                              void* d_out, int out_size, void* d_ws, size_t ws_size,
                              hipStream_t stream) {
  const float* x  = (const float*)d_in[0];
  const int*   ei = (const int*)d_in[1];
  const float* ew = (const float*)d_in[2];
  const float* W1 = (const float*)d_in[3];
  const float* b1 = (const float*)d_in[4];
  const float* W2 = (const float*)d_in[5];
  const float* b2 = (const float*)d_in[6];
  float* out = (float*)d_out;

  const int* row = ei;            // edge_index[0]
  const int* col = ei + N_EDGES;  // edge_index[1]

  char* ws = (char*)d_ws;
  size_t off = 0;
  auto alloc = [&](size_t bytes) {
    void* p = ws + off;
    off = (off + bytes + 255) & ~(size_t)255;
    return p;
  };
  unsigned long long* packed = (unsigned long long*)alloc(N_NODES * 8);
  int*   rowptr   = (int*)alloc((N_NODES + 1) * 4);
  float* dinv     = (float*)alloc(N_NODES * 4);
  int*   partials = (int*)alloc(SCAN_NBLK * 4);
  unsigned short* rank = (unsigned short*)alloc((size_t)N_EDGES * 2);
  int2*  ep       = (int2*)alloc((size_t)N_EDGES * 8);
  unsigned short* bufA = (unsigned short*)alloc((size_t)N_NODES * N_HID * 2);   // bf16 x@W1
  float*          bufB = (float*)alloc((size_t)N_NODES * N_HID * 4);            // fp32 h1
  unsigned short* bufC = (unsigned short*)alloc((size_t)N_NODES * N_CLASS * 2); // bf16 h1@W2

  hipMemsetAsync(packed, 0, N_NODES * 8, stream);

  int eblocks = (N_EDGES + 255) / 256;
  int nblocks = (N_NODES + 255) / 256;
  int gblocks = (N_NODES + 63) / 64;  // 782; also covers 782*2048 >= N_EDGES edges

  // fused: layer-1 GEMM + edge histogram/rank
  fused_gemm1_deg_kernel<<<gblocks, 256, 0, stream>>>(x, W1, bufA, col, ew, packed, rank);
  scan1_kernel<<<SCAN_NBLK, 256, 0, stream>>>(packed, rowptr, partials, dinv);
  scan2_kernel<<<1, 64, 0, stream>>>(partials, rowptr);
  scan3_kernel<<<nblocks, 256, 0, stream>>>(rowptr, partials);
  scatter_kernel<<<eblocks, 256, 0, stream>>>(row, col, ew, rank, dinv, rowptr, ep, N_EDGES);

  agg128_kernel<<<(N_NODES * 64 + 255) / 256, 256, 0, stream>>>(
      bufA, rowptr, ep, dinv, b1, bufB, N_NODES);

  gemm_kernel<N_CLASS, 64, N_HID><<<gblocks, 256, 0, stream>>>(bufB, W2, bufC, N_NODES);
  agg64_kernel<<<(N_NODES * 64 + 255) / 256, 256, 0, stream>>>(
      bufC, rowptr, ep, dinv, b2, out, N_NODES);
}

// Round 6
// 398.349 us; speedup vs baseline: 1.1340x; 1.1340x over previous
//
#include <hip/hip_runtime.h>
#include <math.h>

#define N_NODES 50000
#define N_EDGES 1600000
#define N_FEAT  256
#define N_HID   128
#define N_CLASS 64
#define SCAN_NBLK ((N_NODES + 1023) / 1024)
#define FIXSCALE 268435456.0f  // 2^28

__device__ __forceinline__ unsigned short f2bf(float f) {
  unsigned int u = __float_as_uint(f);
  unsigned int r = (u + 0x7fffu + ((u >> 16) & 1u)) >> 16;  // RNE
  return (unsigned short)r;
}

// ---------------- pass A: packed degree/count histogram + per-edge rank ----------------
__global__ __launch_bounds__(256) void deg_rank_kernel(
    const int* __restrict__ col, const float* __restrict__ ew,
    unsigned long long* __restrict__ packed, unsigned short* __restrict__ rank, int E) {
  int e = blockIdx.x * 256 + threadIdx.x;
  if (e >= E) return;
  int c = col[e];
  unsigned long long fix = (unsigned long long)__float2uint_rn(ew[e] * FIXSCALE);
  unsigned long long old = atomicAdd(&packed[c], (1ULL << 40) | fix);
  rank[e] = (unsigned short)(old >> 40);
}

// ---------------- scan1: unpack counts/dinv from packed + block-local exclusive scan ----
__global__ __launch_bounds__(256) void scan1_kernel(
    const unsigned long long* __restrict__ packed, int* __restrict__ rowptr,
    int* __restrict__ partials, float* __restrict__ dinv) {
  __shared__ int wsum[4];
  __shared__ int woff[4];
  int t = threadIdx.x, b = blockIdx.x;
  int base = b * 1024 + t * 4;
  int v0 = 0, v1 = 0, v2 = 0, v3 = 0;
#pragma unroll
  for (int j = 0; j < 4; ++j) {
    int i = base + j;
    if (i < N_NODES) {
      unsigned long long p = packed[i];
      int c = (int)(p >> 40);
      float deg = (float)(long long)(p & 0xFFFFFFFFFFULL) * (1.0f / FIXSCALE);
      dinv[i] = rsqrtf(deg + 1.0f);  // +1 = self-loop weight
      if (j == 0) v0 = c; else if (j == 1) v1 = c; else if (j == 2) v2 = c; else v3 = c;
    }
  }
  int s1 = v0 + v1, s2 = s1 + v2, s3 = s2 + v3;
  int lane = t & 63, w = t >> 6;
  int inc = s3;
#pragma unroll
  for (int off = 1; off < 64; off <<= 1) {
    int u = __shfl_up(inc, off, 64);
    if (lane >= off) inc += u;
  }
  if (lane == 63) wsum[w] = inc;
  __syncthreads();
  if (t == 0) {
    int a = 0;
#pragma unroll
    for (int i = 0; i < 4; ++i) { woff[i] = a; a += wsum[i]; }
    partials[b] = a;
  }
  __syncthreads();
  int ex = woff[w] + inc - s3;
  if (base + 0 < N_NODES) rowptr[base + 0] = ex;
  if (base + 1 < N_NODES) rowptr[base + 1] = ex + v0;
  if (base + 2 < N_NODES) rowptr[base + 2] = ex + s1;
  if (base + 3 < N_NODES) rowptr[base + 3] = ex + s2;
}

__global__ void scan2_kernel(int* __restrict__ partials, int* __restrict__ rowptr) {
  if (threadIdx.x == 0 && blockIdx.x == 0) {
    int a = 0;
    for (int i = 0; i < SCAN_NBLK; ++i) { int x = partials[i]; partials[i] = a; a += x; }
    rowptr[N_NODES] = a;  // == N_EDGES
  }
}

__global__ __launch_bounds__(256) void scan3_kernel(
    int* __restrict__ rowptr, const int* __restrict__ partials) {
  int i = blockIdx.x * 256 + threadIdx.x;
  if (i < N_NODES) rowptr[i] += partials[i >> 10];
}

// ---------------- atomic-free scatter into CSC ----------------
__global__ __launch_bounds__(256) void scatter_kernel(
    const int* __restrict__ row, const int* __restrict__ col,
    const float* __restrict__ ew, const unsigned short* __restrict__ rank,
    const float* __restrict__ dinv, const int* __restrict__ rowptr,
    int2* __restrict__ ep, int E) {
  int e = blockIdx.x * 256 + threadIdx.x;
  if (e >= E) return;
  int r = row[e], c = col[e];
  float w = dinv[r] * ew[e] * dinv[c];
  int pos = rowptr[c] + (int)rank[e];
  ep[pos] = make_int2(r, __float_as_int(w));
}

// ---------------- fp32 GEMM with bf16 output ----------------
template <int BN, int BK, int K>
__global__ __launch_bounds__(256) void gemm_kernel(
    const float* __restrict__ A, const float* __restrict__ B,
    unsigned short* __restrict__ C, int M) {
  constexpr int BM = 64;
  constexpr int TC = BN / 4;
  constexpr int TR = 256 / TC;
  constexpr int RM = BM / TR;
  __shared__ float As[BM][BK + 4];
  __shared__ float Bs[BK][BN];

  int t  = threadIdx.x;
  int m0 = blockIdx.x * BM;
  int tc = t % TC, tr = t / TC;

  float acc[RM][4];
#pragma unroll
  for (int r = 0; r < RM; ++r)
#pragma unroll
    for (int c = 0; c < 4; ++c) acc[r][c] = 0.f;

  for (int k0 = 0; k0 < K; k0 += BK) {
    constexpr int F4R = BK / 4;
#pragma unroll
    for (int p = 0; p < (BM * F4R) / 256; ++p) {
      int row = t / F4R + p * (256 / F4R);
      int c4  = t % F4R;
      int gr  = m0 + row;
      float4 v = make_float4(0.f, 0.f, 0.f, 0.f);
      if (gr < M) v = *(const float4*)&A[(size_t)gr * K + k0 + c4 * 4];
      *(float4*)&As[row][c4 * 4] = v;
    }
    constexpr int BF4 = BK * BN / 4;
#pragma unroll
    for (int p = 0; p < BF4 / 256; ++p) {
      int idx = p * 256 + t;
      int row = idx / (BN / 4), c4 = idx % (BN / 4);
      *(float4*)&Bs[row][c4 * 4] = *(const float4*)&B[(size_t)(k0 + row) * BN + c4 * 4];
    }
    __syncthreads();

    for (int kk = 0; kk < BK; kk += 4) {
      float4 b0 = *(const float4*)&Bs[kk + 0][tc * 4];
      float4 b1 = *(const float4*)&Bs[kk + 1][tc * 4];
      float4 b2 = *(const float4*)&Bs[kk + 2][tc * 4];
      float4 b3 = *(const float4*)&Bs[kk + 3][tc * 4];
#pragma unroll
      for (int r = 0; r < RM; ++r) {
        float4 a = *(const float4*)&As[tr * RM + r][kk];
        acc[r][0] = fmaf(a.x, b0.x, fmaf(a.y, b1.x, fmaf(a.z, b2.x, fmaf(a.w, b3.x, acc[r][0]))));
        acc[r][1] = fmaf(a.x, b0.y, fmaf(a.y, b1.y, fmaf(a.z, b2.y, fmaf(a.w, b3.y, acc[r][1]))));
        acc[r][2] = fmaf(a.x, b0.z, fmaf(a.y, b1.z, fmaf(a.z, b2.z, fmaf(a.w, b3.z, acc[r][2]))));
        acc[r][3] = fmaf(a.x, b0.w, fmaf(a.y, b1.w, fmaf(a.z, b2.w, fmaf(a.w, b3.w, acc[r][3]))));
      }
    }
    __syncthreads();
  }
#pragma unroll
  for (int r = 0; r < RM; ++r) {
    int gr = m0 + tr * RM + r;
    if (gr < M) {
      uint2 o;
      o.x = (unsigned int)f2bf(acc[r][0]) | ((unsigned int)f2bf(acc[r][1]) << 16);
      o.y = (unsigned int)f2bf(acc[r][2]) | ((unsigned int)f2bf(acc[r][3]) << 16);
      *(uint2*)&C[(size_t)gr * BN + tc * 4] = o;
    }
  }
}

// ---------------- aggregation D=128: 4 gathers in flight per wave ----------------
__global__ __launch_bounds__(256) void agg128_kernel(
    const unsigned short* __restrict__ h, const int* __restrict__ rowptr,
    const int2* __restrict__ ep, const float* __restrict__ dinv,
    const float* __restrict__ bias, float* __restrict__ out, int n) {
  int wid  = (int)((blockIdx.x * 256 + threadIdx.x) >> 6);
  int lane = threadIdx.x & 63;
  if (wid >= n) return;
  int s = rowptr[wid], e_end = rowptr[wid + 1];
  unsigned int f2 = 2u * lane;
  float a0 = 0.f, a1 = 0.f, b0 = 0.f, b1 = 0.f,
        c0 = 0.f, c1 = 0.f, d0 = 0.f, d1 = 0.f;
  int e = s;
  for (; e + 3 < e_end; e += 4) {
    int2 p0 = ep[e], p1 = ep[e + 1], p2 = ep[e + 2], p3 = ep[e + 3];
    unsigned int h0 = *(const unsigned int*)(h + ((size_t)p0.x << 7) + f2);
    unsigned int h1 = *(const unsigned int*)(h + ((size_t)p1.x << 7) + f2);
    unsigned int h2 = *(const unsigned int*)(h + ((size_t)p2.x << 7) + f2);
    unsigned int h3 = *(const unsigned int*)(h + ((size_t)p3.x << 7) + f2);
    float w0 = __int_as_float(p0.y), w1 = __int_as_float(p1.y);
    float w2 = __int_as_float(p2.y), w3 = __int_as_float(p3.y);
    a0 = fmaf(w0, __uint_as_float(h0 << 16), a0);
    a1 = fmaf(w0, __uint_as_float(h0 & 0xffff0000u), a1);
    b0 = fmaf(w1, __uint_as_float(h1 << 16), b0);
    b1 = fmaf(w1, __uint_as_float(h1 & 0xffff0000u), b1);
    c0 = fmaf(w2, __uint_as_float(h2 << 16), c0);
    c1 = fmaf(w2, __uint_as_float(h2 & 0xffff0000u), c1);
    d0 = fmaf(w3, __uint_as_float(h3 << 16), d0);
    d1 = fmaf(w3, __uint_as_float(h3 & 0xffff0000u), d1);
  }
  for (; e < e_end; ++e) {
    int2 p0 = ep[e];
    unsigned int h0 = *(const unsigned int*)(h + ((size_t)p0.x << 7) + f2);
    float w0 = __int_as_float(p0.y);
    a0 = fmaf(w0, __uint_as_float(h0 << 16), a0);
    a1 = fmaf(w0, __uint_as_float(h0 & 0xffff0000u), a1);
  }
  float di = dinv[wid], sw = di * di;
  unsigned int hs = *(const unsigned int*)(h + ((size_t)wid << 7) + f2);
  a0 = fmaf(sw, __uint_as_float(hs << 16), a0);
  a1 = fmaf(sw, __uint_as_float(hs & 0xffff0000u), a1);
  float v0 = (a0 + b0) + (c0 + d0) + bias[f2];
  float v1 = (a1 + b1) + (c1 + d1) + bias[f2 + 1];
  v0 = 1.f / (1.f + expf(-v0));
  v1 = 1.f / (1.f + expf(-v1));
  *(float2*)&out[((size_t)wid << 7) + f2] = make_float2(v0, v1);
}

// ---------------- aggregation D=64: lane-halves, 4 gathers in flight per half ----------------
__global__ __launch_bounds__(256) void agg64_kernel(
    const unsigned short* __restrict__ h, const int* __restrict__ rowptr,
    const int2* __restrict__ ep, const float* __restrict__ dinv,
    const float* __restrict__ bias, float* __restrict__ out, int n) {
  int wid  = (int)((blockIdx.x * 256 + threadIdx.x) >> 6);
  int lane = threadIdx.x & 63;
  if (wid >= n) return;
  int half = lane >> 5, ll = lane & 31;
  unsigned int f2 = 2u * ll;
  int s = rowptr[wid], e_end = rowptr[wid + 1];
  float a0 = 0.f, a1 = 0.f, b0 = 0.f, b1 = 0.f,
        c0 = 0.f, c1 = 0.f, d0 = 0.f, d1 = 0.f;
  int e = s + half;
  for (; e + 6 < e_end; e += 8) {
    int2 p0 = ep[e], p1 = ep[e + 2], p2 = ep[e + 4], p3 = ep[e + 6];
    unsigned int h0 = *(const unsigned int*)(h + ((size_t)p0.x << 6) + f2);
    unsigned int h1 = *(const unsigned int*)(h + ((size_t)p1.x << 6) + f2);
    unsigned int h2 = *(const unsigned int*)(h + ((size_t)p2.x << 6) + f2);
    unsigned int h3 = *(const unsigned int*)(h + ((size_t)p3.x << 6) + f2);
    float w0 = __int_as_float(p0.y), w1 = __int_as_float(p1.y);
    float w2 = __int_as_float(p2.y), w3 = __int_as_float(p3.y);
    a0 = fmaf(w0, __uint_as_float(h0 << 16), a0);
    a1 = fmaf(w0, __uint_as_float(h0 & 0xffff0000u), a1);
    b0 = fmaf(w1, __uint_as_float(h1 << 16), b0);
    b1 = fmaf(w1, __uint_as_float(h1 & 0xffff0000u), b1);
    c0 = fmaf(w2, __uint_as_float(h2 << 16), c0);
    c1 = fmaf(w2, __uint_as_float(h2 & 0xffff0000u), c1);
    d0 = fmaf(w3, __uint_as_float(h3 << 16), d0);
    d1 = fmaf(w3, __uint_as_float(h3 & 0xffff0000u), d1);
  }
  for (; e < e_end; e += 2) {
    int2 p0 = ep[e];
    unsigned int h0 = *(const unsigned int*)(h + ((size_t)p0.x << 6) + f2);
    float w0 = __int_as_float(p0.y);
    a0 = fmaf(w0, __uint_as_float(h0 << 16), a0);
    a1 = fmaf(w0, __uint_as_float(h0 & 0xffff0000u), a1);
  }
  a0 = (a0 + b0) + (c0 + d0);
  a1 = (a1 + b1) + (c1 + d1);
  if (half == 0) {  // self-loop term exactly once
    float di = dinv[wid], sw = di * di;
    unsigned int hs = *(const unsigned int*)(h + ((size_t)wid << 6) + f2);
    a0 = fmaf(sw, __uint_as_float(hs << 16), a0);
    a1 = fmaf(sw, __uint_as_float(hs & 0xffff0000u), a1);
  }
  a0 += __shfl_xor(a0, 32, 64);
  a1 += __shfl_xor(a1, 32, 64);
  if (half == 0) {
    float v0 = tanhf(a0 + bias[f2]);
    float v1 = tanhf(a1 + bias[f2 + 1]);
    *(float2*)&out[(size_t)wid * 64 + f2] = make_float2(v0, v1);
  }
}

extern "C" void kernel_launch(void* const* d_in, const int* in_sizes, int n_in,
                              void* d_out, int out_size, void* d_ws, size_t ws_size,
                              hipStream_t stream) {
  const float* x  = (const float*)d_in[0];
  const int*   ei = (const int*)d_in[1];
  const float* ew = (const float*)d_in[2];
  const float* W1 = (const float*)d_in[3];
  const float* b1 = (const float*)d_in[4];
  const float* W2 = (const float*)d_in[5];
  const float* b2 = (const float*)d_in[6];
  float* out = (float*)d_out;

  const int* row = ei;            // edge_index[0]
  const int* col = ei + N_EDGES;  // edge_index[1]

  char* ws = (char*)d_ws;
  size_t off = 0;
  auto alloc = [&](size_t bytes) {
    void* p = ws + off;
    off = (off + bytes + 255) & ~(size_t)255;
    return p;
  };
  unsigned long long* packed = (unsigned long long*)alloc(N_NODES * 8);
  int*   rowptr   = (int*)alloc((N_NODES + 1) * 4);
  float* dinv     = (float*)alloc(N_NODES * 4);
  int*   partials = (int*)alloc(SCAN_NBLK * 4);
  unsigned short* rank = (unsigned short*)alloc((size_t)N_EDGES * 2);
  int2*  ep       = (int2*)alloc((size_t)N_EDGES * 8);
  unsigned short* bufA = (unsigned short*)alloc((size_t)N_NODES * N_HID * 2);   // bf16 x@W1
  float*          bufB = (float*)alloc((size_t)N_NODES * N_HID * 4);            // fp32 h1
  unsigned short* bufC = (unsigned short*)alloc((size_t)N_NODES * N_CLASS * 2); // bf16 h1@W2

  hipMemsetAsync(packed, 0, N_NODES * 8, stream);

  int eblocks = (N_EDGES + 255) / 256;
  int nblocks = (N_NODES + 255) / 256;
  int gblocks = (N_NODES + 63) / 64;

  deg_rank_kernel<<<eblocks, 256, 0, stream>>>(col, ew, packed, rank, N_EDGES);
  scan1_kernel<<<SCAN_NBLK, 256, 0, stream>>>(packed, rowptr, partials, dinv);
  scan2_kernel<<<1, 64, 0, stream>>>(partials, rowptr);
  scan3_kernel<<<nblocks, 256, 0, stream>>>(rowptr, partials);
  scatter_kernel<<<eblocks, 256, 0, stream>>>(row, col, ew, rank, dinv, rowptr, ep, N_EDGES);

  // layer 1: h1 = sigmoid(A @ (x @ W1) + b1)
  gemm_kernel<N_HID, 64, N_FEAT><<<gblocks, 256, 0, stream>>>(x, W1, bufA, N_NODES);
  agg128_kernel<<<(N_NODES * 64 + 255) / 256, 256, 0, stream>>>(
      bufA, rowptr, ep, dinv, b1, bufB, N_NODES);

  // layer 2: out = tanh(A @ (h1 @ W2) + b2)
  gemm_kernel<N_CLASS, 64, N_HID><<<gblocks, 256, 0, stream>>>(bufB, W2, bufC, N_NODES);
  agg64_kernel<<<(N_NODES * 64 + 255) / 256, 256, 0, stream>>>(
      bufC, rowptr, ep, dinv, b2, out, N_NODES);
}

// Round 7
// 350.016 us; speedup vs baseline: 1.2906x; 1.1381x over previous
//
#include <hip/hip_runtime.h>
#include <math.h>

#define N_NODES 50000
#define N_EDGES 1600000
#define N_FEAT  256
#define N_HID   128
#define N_CLASS 64
#define SCAN_NBLK ((N_NODES + 1023) / 1024)
#define FIXSCALE 268435456.0f  // 2^28

typedef __attribute__((ext_vector_type(8))) short short8v;
typedef __attribute__((ext_vector_type(4))) float float4v;

__device__ __forceinline__ unsigned int f2bf(float f) {
  unsigned int u = __float_as_uint(f);
  unsigned int r = (u + 0x7fffu + ((u >> 16) & 1u)) >> 16;  // RNE
  return r & 0xffffu;
}

// ---------------- weight transpose + bf16 convert: WT[n][k] = bf16(W[k][n]) ----------------
__global__ __launch_bounds__(256) void transpose_w_kernel(
    const float* __restrict__ W, unsigned short* __restrict__ WT, int K, int N) {
  int i = blockIdx.x * 256 + threadIdx.x;
  if (i >= N * K) return;
  int n = i / K, k = i % K;
  WT[i] = (unsigned short)f2bf(W[(size_t)k * N + n]);
}

// ---------------- pass A: packed degree/count histogram + per-edge rank ----------------
__global__ __launch_bounds__(256) void deg_rank_kernel(
    const int* __restrict__ col, const float* __restrict__ ew,
    unsigned long long* __restrict__ packed, unsigned short* __restrict__ rank, int E) {
  int e = blockIdx.x * 256 + threadIdx.x;
  if (e >= E) return;
  int c = col[e];
  unsigned long long fix = (unsigned long long)__float2uint_rn(ew[e] * FIXSCALE);
  unsigned long long old = atomicAdd(&packed[c], (1ULL << 40) | fix);
  rank[e] = (unsigned short)(old >> 40);
}

// ---------------- scan1: unpack counts/dinv + block-local exclusive scan ----------------
__global__ __launch_bounds__(256) void scan1_kernel(
    const unsigned long long* __restrict__ packed, int* __restrict__ rowptr,
    int* __restrict__ partials, float* __restrict__ dinv) {
  __shared__ int wsum[4];
  __shared__ int woff[4];
  int t = threadIdx.x, b = blockIdx.x;
  int base = b * 1024 + t * 4;
  int v0 = 0, v1 = 0, v2 = 0, v3 = 0;
#pragma unroll
  for (int j = 0; j < 4; ++j) {
    int i = base + j;
    if (i < N_NODES) {
      unsigned long long p = packed[i];
      int c = (int)(p >> 40);
      float deg = (float)(long long)(p & 0xFFFFFFFFFFULL) * (1.0f / FIXSCALE);
      dinv[i] = rsqrtf(deg + 1.0f);  // +1 = self-loop weight
      if (j == 0) v0 = c; else if (j == 1) v1 = c; else if (j == 2) v2 = c; else v3 = c;
    }
  }
  int s1 = v0 + v1, s2 = s1 + v2, s3 = s2 + v3;
  int lane = t & 63, w = t >> 6;
  int inc = s3;
#pragma unroll
  for (int off = 1; off < 64; off <<= 1) {
    int u = __shfl_up(inc, off, 64);
    if (lane >= off) inc += u;
  }
  if (lane == 63) wsum[w] = inc;
  __syncthreads();
  if (t == 0) {
    int a = 0;
#pragma unroll
    for (int i = 0; i < 4; ++i) { woff[i] = a; a += wsum[i]; }
    partials[b] = a;
  }
  __syncthreads();
  int ex = woff[w] + inc - s3;
  if (base + 0 < N_NODES) rowptr[base + 0] = ex;
  if (base + 1 < N_NODES) rowptr[base + 1] = ex + v0;
  if (base + 2 < N_NODES) rowptr[base + 2] = ex + s1;
  if (base + 3 < N_NODES) rowptr[base + 3] = ex + s2;
}

__global__ void scan2_kernel(int* __restrict__ partials, int* __restrict__ rowptr) {
  if (threadIdx.x == 0 && blockIdx.x == 0) {
    int a = 0;
    for (int i = 0; i < SCAN_NBLK; ++i) { int x = partials[i]; partials[i] = a; a += x; }
    rowptr[N_NODES] = a;  // == N_EDGES
  }
}

__global__ __launch_bounds__(256) void scan3_kernel(
    int* __restrict__ rowptr, const int* __restrict__ partials) {
  int i = blockIdx.x * 256 + threadIdx.x;
  if (i < N_NODES) rowptr[i] += partials[i >> 10];
}

// ---------------- atomic-free scatter into CSC ----------------
__global__ __launch_bounds__(256) void scatter_kernel(
    const int* __restrict__ row, const int* __restrict__ col,
    const float* __restrict__ ew, const unsigned short* __restrict__ rank,
    const float* __restrict__ dinv, const int* __restrict__ rowptr,
    int2* __restrict__ ep, int E) {
  int e = blockIdx.x * 256 + threadIdx.x;
  if (e >= E) return;
  int r = row[e], c = col[e];
  float w = dinv[r] * ew[e] * dinv[c];
  int pos = rowptr[c] + (int)rank[e];
  ep[pos] = make_int2(r, __float_as_int(w));
}

// ---------------- bf16 MFMA GEMM: C[M x BN] = A[M x K] @ B[K x BN], BT[BN][K] bf16 ----
// BM=64, 4 waves x 16-row strips; BK=64; LDS rows 128B with XOR-window swizzle.
template <int BN, int K, bool AFP32>
__global__ __launch_bounds__(256) void mfma_gemm_kernel(
    const void* __restrict__ Ain, const unsigned short* __restrict__ BT,
    unsigned short* __restrict__ C, int M) {
  constexpr int BM = 64, BK = 64;
  constexpr int NT = BN / 16;
  __shared__ unsigned char AsB[BM * 128];
  __shared__ unsigned char BsB[BN * 128];
  int t = threadIdx.x;
  int lane = t & 63, wv = t >> 6;
  int m0 = blockIdx.x * BM;

  float4v acc[NT];
#pragma unroll
  for (int i = 0; i < NT; ++i) acc[i] = (float4v){0.f, 0.f, 0.f, 0.f};

  for (int k0 = 0; k0 < K; k0 += BK) {
    // ---- stage A: 64 rows x 64 bf16 (128B/row) ----
    {
      int r = t >> 2, q = t & 3;
      int gr = m0 + r;
      unsigned int swz = (unsigned int)((r & 7) << 4);
      uint4 o0 = make_uint4(0, 0, 0, 0), o1 = make_uint4(0, 0, 0, 0);
      if constexpr (AFP32) {
        const float* A = (const float*)Ain;
        if (gr < M) {
          const float* p = &A[(size_t)gr * K + k0 + q * 16];
          float4 v0 = *(const float4*)(p + 0), v1 = *(const float4*)(p + 4);
          float4 v2 = *(const float4*)(p + 8), v3 = *(const float4*)(p + 12);
          o0.x = f2bf(v0.x) | (f2bf(v0.y) << 16); o0.y = f2bf(v0.z) | (f2bf(v0.w) << 16);
          o0.z = f2bf(v1.x) | (f2bf(v1.y) << 16); o0.w = f2bf(v1.z) | (f2bf(v1.w) << 16);
          o1.x = f2bf(v2.x) | (f2bf(v2.y) << 16); o1.y = f2bf(v2.z) | (f2bf(v2.w) << 16);
          o1.z = f2bf(v3.x) | (f2bf(v3.y) << 16); o1.w = f2bf(v3.z) | (f2bf(v3.w) << 16);
        }
      } else {
        const unsigned short* A = (const unsigned short*)Ain;
        if (gr < M) {
          const unsigned short* p = &A[(size_t)gr * K + k0 + q * 16];
          o0 = *(const uint4*)(p);
          o1 = *(const uint4*)(p + 8);
        }
      }
      *(uint4*)(AsB + r * 128 + (((unsigned)(q * 32)) ^ swz)) = o0;
      *(uint4*)(AsB + r * 128 + (((unsigned)(q * 32 + 16)) ^ swz)) = o1;
    }
    // ---- stage B: BN rows x 64 bf16 (128B/row) from BT[BN][K] ----
    {
      constexpr int BPT = BN / 2;        // bytes per thread: 64 (BN=128) / 32 (BN=64)
      constexpr int TPR = 128 / BPT;     // threads per row: 2 / 4
      int br = t / TPR;
      int bo = (t % TPR) * BPT;
      unsigned int swz = (unsigned int)((br & 7) << 4);
#pragma unroll
      for (int s = 0; s < BPT / 16; ++s) {
        uint4 v = *(const uint4*)&BT[(size_t)br * K + k0 + (bo + s * 16) / 2];
        *(uint4*)(BsB + br * 128 + (((unsigned)(bo + s * 16)) ^ swz)) = v;
      }
    }
    __syncthreads();
    // ---- MFMA ----
    {
      int ar = wv * 16 + (lane & 15);
      int g = lane >> 4;
      unsigned int aswz = (unsigned int)((ar & 7) << 4);
      unsigned int bswz = (unsigned int)((lane & 7) << 4);
#pragma unroll
      for (int kk = 0; kk < BK; kk += 32) {
        short8v af = *(const short8v*)(AsB + ar * 128 +
                                       (((unsigned)(kk * 2 + g * 16)) ^ aswz));
#pragma unroll
        for (int nt = 0; nt < NT; ++nt) {
          int brr = nt * 16 + (lane & 15);
          short8v bf = *(const short8v*)(BsB + brr * 128 +
                                         (((unsigned)(kk * 2 + g * 16)) ^ bswz));
          acc[nt] = __builtin_amdgcn_mfma_f32_16x16x32_bf16(af, bf, acc[nt], 0, 0, 0);
        }
      }
    }
    __syncthreads();
  }
  // ---- epilogue: D col=lane&15, row=(lane>>4)*4+j (m89-verified) ----
  int r0 = m0 + wv * 16 + (lane >> 4) * 4;
  int c0 = lane & 15;
#pragma unroll
  for (int nt = 0; nt < NT; ++nt) {
#pragma unroll
    for (int j = 0; j < 4; ++j) {
      int gr = r0 + j;
      if (gr < M) C[(size_t)gr * BN + nt * 16 + c0] = (unsigned short)f2bf(acc[nt][j]);
    }
  }
}

// ---------------- aggregation D=128: 4 gathers in flight; bf16 output ----------------
__global__ __launch_bounds__(256) void agg128_kernel(
    const unsigned short* __restrict__ h, const int* __restrict__ rowptr,
    const int2* __restrict__ ep, const float* __restrict__ dinv,
    const float* __restrict__ bias, unsigned short* __restrict__ out, int n) {
  int wid  = (int)((blockIdx.x * 256 + threadIdx.x) >> 6);
  int lane = threadIdx.x & 63;
  if (wid >= n) return;
  int s = rowptr[wid], e_end = rowptr[wid + 1];
  unsigned int f2 = 2u * lane;
  float a0 = 0.f, a1 = 0.f, b0 = 0.f, b1 = 0.f,
        c0 = 0.f, c1 = 0.f, d0 = 0.f, d1 = 0.f;
  int e = s;
  for (; e + 3 < e_end; e += 4) {
    int2 p0 = ep[e], p1 = ep[e + 1], p2 = ep[e + 2], p3 = ep[e + 3];
    unsigned int h0 = *(const unsigned int*)(h + ((size_t)p0.x << 7) + f2);
    unsigned int h1 = *(const unsigned int*)(h + ((size_t)p1.x << 7) + f2);
    unsigned int h2 = *(const unsigned int*)(h + ((size_t)p2.x << 7) + f2);
    unsigned int h3 = *(const unsigned int*)(h + ((size_t)p3.x << 7) + f2);
    float w0 = __int_as_float(p0.y), w1 = __int_as_float(p1.y);
    float w2 = __int_as_float(p2.y), w3 = __int_as_float(p3.y);
    a0 = fmaf(w0, __uint_as_float(h0 << 16), a0);
    a1 = fmaf(w0, __uint_as_float(h0 & 0xffff0000u), a1);
    b0 = fmaf(w1, __uint_as_float(h1 << 16), b0);
    b1 = fmaf(w1, __uint_as_float(h1 & 0xffff0000u), b1);
    c0 = fmaf(w2, __uint_as_float(h2 << 16), c0);
    c1 = fmaf(w2, __uint_as_float(h2 & 0xffff0000u), c1);
    d0 = fmaf(w3, __uint_as_float(h3 << 16), d0);
    d1 = fmaf(w3, __uint_as_float(h3 & 0xffff0000u), d1);
  }
  for (; e < e_end; ++e) {
    int2 p0 = ep[e];
    unsigned int h0 = *(const unsigned int*)(h + ((size_t)p0.x << 7) + f2);
    float w0 = __int_as_float(p0.y);
    a0 = fmaf(w0, __uint_as_float(h0 << 16), a0);
    a1 = fmaf(w0, __uint_as_float(h0 & 0xffff0000u), a1);
  }
  float di = dinv[wid], sw = di * di;
  unsigned int hs = *(const unsigned int*)(h + ((size_t)wid << 7) + f2);
  a0 = fmaf(sw, __uint_as_float(hs << 16), a0);
  a1 = fmaf(sw, __uint_as_float(hs & 0xffff0000u), a1);
  float v0 = (a0 + b0) + (c0 + d0) + bias[f2];
  float v1 = (a1 + b1) + (c1 + d1) + bias[f2 + 1];
  v0 = 1.f / (1.f + expf(-v0));
  v1 = 1.f / (1.f + expf(-v1));
  unsigned int o = f2bf(v0) | (f2bf(v1) << 16);
  *(unsigned int*)(out + ((size_t)wid << 7) + f2) = o;
}

// ---------------- aggregation D=64: lane-halves, 4 gathers in flight per half ----------------
__global__ __launch_bounds__(256) void agg64_kernel(
    const unsigned short* __restrict__ h, const int* __restrict__ rowptr,
    const int2* __restrict__ ep, const float* __restrict__ dinv,
    const float* __restrict__ bias, float* __restrict__ out, int n) {
  int wid  = (int)((blockIdx.x * 256 + threadIdx.x) >> 6);
  int lane = threadIdx.x & 63;
  if (wid >= n) return;
  int half = lane >> 5, ll = lane & 31;
  unsigned int f2 = 2u * ll;
  int s = rowptr[wid], e_end = rowptr[wid + 1];
  float a0 = 0.f, a1 = 0.f, b0 = 0.f, b1 = 0.f,
        c0 = 0.f, c1 = 0.f, d0 = 0.f, d1 = 0.f;
  int e = s + half;
  for (; e + 6 < e_end; e += 8) {
    int2 p0 = ep[e], p1 = ep[e + 2], p2 = ep[e + 4], p3 = ep[e + 6];
    unsigned int h0 = *(const unsigned int*)(h + ((size_t)p0.x << 6) + f2);
    unsigned int h1 = *(const unsigned int*)(h + ((size_t)p1.x << 6) + f2);
    unsigned int h2 = *(const unsigned int*)(h + ((size_t)p2.x << 6) + f2);
    unsigned int h3 = *(const unsigned int*)(h + ((size_t)p3.x << 6) + f2);
    float w0 = __int_as_float(p0.y), w1 = __int_as_float(p1.y);
    float w2 = __int_as_float(p2.y), w3 = __int_as_float(p3.y);
    a0 = fmaf(w0, __uint_as_float(h0 << 16), a0);
    a1 = fmaf(w0, __uint_as_float(h0 & 0xffff0000u), a1);
    b0 = fmaf(w1, __uint_as_float(h1 << 16), b0);
    b1 = fmaf(w1, __uint_as_float(h1 & 0xffff0000u), b1);
    c0 = fmaf(w2, __uint_as_float(h2 << 16), c0);
    c1 = fmaf(w2, __uint_as_float(h2 & 0xffff0000u), c1);
    d0 = fmaf(w3, __uint_as_float(h3 << 16), d0);
    d1 = fmaf(w3, __uint_as_float(h3 & 0xffff0000u), d1);
  }
  for (; e < e_end; e += 2) {
    int2 p0 = ep[e];
    unsigned int h0 = *(const unsigned int*)(h + ((size_t)p0.x << 6) + f2);
    float w0 = __int_as_float(p0.y);
    a0 = fmaf(w0, __uint_as_float(h0 << 16), a0);
    a1 = fmaf(w0, __uint_as_float(h0 & 0xffff0000u), a1);
  }
  a0 = (a0 + b0) + (c0 + d0);
  a1 = (a1 + b1) + (c1 + d1);
  if (half == 0) {  // self-loop term exactly once
    float di = dinv[wid], sw = di * di;
    unsigned int hs = *(const unsigned int*)(h + ((size_t)wid << 6) + f2);
    a0 = fmaf(sw, __uint_as_float(hs << 16), a0);
    a1 = fmaf(sw, __uint_as_float(hs & 0xffff0000u), a1);
  }
  a0 += __shfl_xor(a0, 32, 64);
  a1 += __shfl_xor(a1, 32, 64);
  if (half == 0) {
    float v0 = tanhf(a0 + bias[f2]);
    float v1 = tanhf(a1 + bias[f2 + 1]);
    *(float2*)&out[(size_t)wid * 64 + f2] = make_float2(v0, v1);
  }
}

extern "C" void kernel_launch(void* const* d_in, const int* in_sizes, int n_in,
                              void* d_out, int out_size, void* d_ws, size_t ws_size,
                              hipStream_t stream) {
  const float* x  = (const float*)d_in[0];
  const int*   ei = (const int*)d_in[1];
  const float* ew = (const float*)d_in[2];
  const float* W1 = (const float*)d_in[3];
  const float* b1 = (const float*)d_in[4];
  const float* W2 = (const float*)d_in[5];
  const float* b2 = (const float*)d_in[6];
  float* out = (float*)d_out;

  const int* row = ei;            // edge_index[0]
  const int* col = ei + N_EDGES;  // edge_index[1]

  char* ws = (char*)d_ws;
  size_t off = 0;
  auto alloc = [&](size_t bytes) {
    void* p = ws + off;
    off = (off + bytes + 255) & ~(size_t)255;
    return p;
  };
  unsigned long long* packed = (unsigned long long*)alloc(N_NODES * 8);
  int*   rowptr   = (int*)alloc((N_NODES + 1) * 4);
  float* dinv     = (float*)alloc(N_NODES * 4);
  int*   partials = (int*)alloc(SCAN_NBLK * 4);
  unsigned short* rank = (unsigned short*)alloc((size_t)N_EDGES * 2);
  int2*  ep       = (int2*)alloc((size_t)N_EDGES * 8);
  unsigned short* W1T  = (unsigned short*)alloc((size_t)N_HID * N_FEAT * 2);
  unsigned short* W2T  = (unsigned short*)alloc((size_t)N_CLASS * N_HID * 2);
  unsigned short* bufA = (unsigned short*)alloc((size_t)N_NODES * N_HID * 2);   // bf16 x@W1
  unsigned short* bufB = (unsigned short*)alloc((size_t)N_NODES * N_HID * 2);   // bf16 h1
  unsigned short* bufC = (unsigned short*)alloc((size_t)N_NODES * N_CLASS * 2); // bf16 h1@W2

  hipMemsetAsync(packed, 0, N_NODES * 8, stream);

  int eblocks = (N_EDGES + 255) / 256;
  int nblocks = (N_NODES + 255) / 256;
  int gblocks = (N_NODES + 63) / 64;

  transpose_w_kernel<<<(N_HID * N_FEAT + 255) / 256, 256, 0, stream>>>(W1, W1T, N_FEAT, N_HID);
  transpose_w_kernel<<<(N_CLASS * N_HID + 255) / 256, 256, 0, stream>>>(W2, W2T, N_HID, N_CLASS);

  deg_rank_kernel<<<eblocks, 256, 0, stream>>>(col, ew, packed, rank, N_EDGES);
  scan1_kernel<<<SCAN_NBLK, 256, 0, stream>>>(packed, rowptr, partials, dinv);
  scan2_kernel<<<1, 64, 0, stream>>>(partials, rowptr);
  scan3_kernel<<<nblocks, 256, 0, stream>>>(rowptr, partials);
  scatter_kernel<<<eblocks, 256, 0, stream>>>(row, col, ew, rank, dinv, rowptr, ep, N_EDGES);

  // layer 1: h1 = sigmoid(A @ (x @ W1) + b1)
  mfma_gemm_kernel<N_HID, N_FEAT, true><<<gblocks, 256, 0, stream>>>(x, W1T, bufA, N_NODES);
  agg128_kernel<<<(N_NODES * 64 + 255) / 256, 256, 0, stream>>>(
      bufA, rowptr, ep, dinv, b1, bufB, N_NODES);

  // layer 2: out = tanh(A @ (h1 @ W2) + b2)
  mfma_gemm_kernel<N_CLASS, N_HID, false><<<gblocks, 256, 0, stream>>>(bufB, W2T, bufC, N_NODES);
  agg64_kernel<<<(N_NODES * 64 + 255) / 256, 256, 0, stream>>>(
      bufC, rowptr, ep, dinv, b2, out, N_NODES);
}

// Round 8
// 345.252 us; speedup vs baseline: 1.3084x; 1.0138x over previous
//
#include <hip/hip_runtime.h>
#include <hip/hip_fp16.h>
#include <math.h>

#define N_NODES 50000
#define N_EDGES 1600000
#define N_FEAT  256
#define N_HID   128
#define N_CLASS 64
#define SCAN_NBLK ((N_NODES + 1023) / 1024)
#define FIXSCALE 268435456.0f  // 2^28
#define EBLK ((N_EDGES + 255) / 256)   // 6250 edge blocks
#define GBLK ((N_NODES + 63) / 64)     // 782 gemm blocks

typedef __attribute__((ext_vector_type(8))) short short8v;
typedef __attribute__((ext_vector_type(4))) float float4v;

__device__ __forceinline__ unsigned int f2bf(float f) {
  unsigned int u = __float_as_uint(f);
  unsigned int r = (u + 0x7fffu + ((u >> 16) & 1u)) >> 16;  // RNE
  return r & 0xffffu;
}

// ---------------- MFMA GEMM body: C[M x BN] bf16 = A[M x K] @ W[K x BN](fp32) ----
// BM=64, 4 waves x 16-row strips, BK=64. LDS rows 128B, XOR-window swizzle (r&7)<<4.
// B is staged from fp32 W[k][n] directly (convert + transpose into LDS).
template <int BN, int K, bool AFP32>
__device__ __forceinline__ void gemm_body(
    const void* __restrict__ Ain, const float* __restrict__ W,
    unsigned short* __restrict__ C, int M, int m0) {
  constexpr int BM = 64, BK = 64;
  constexpr int NT = BN / 16;
  __shared__ unsigned char AsB[BM * 128];
  __shared__ unsigned char BsB[BN * 128];
  int t = threadIdx.x;
  int lane = t & 63, wv = t >> 6;

  float4v acc[NT];
#pragma unroll
  for (int i = 0; i < NT; ++i) acc[i] = (float4v){0.f, 0.f, 0.f, 0.f};

  for (int k0 = 0; k0 < K; k0 += BK) {
    // ---- stage A: 64 rows x 64 bf16 (128B/row) ----
    {
      int r = t >> 2, q = t & 3;
      int gr = m0 + r;
      unsigned int swz = (unsigned int)((r & 7) << 4);
      uint4 o0 = make_uint4(0, 0, 0, 0), o1 = make_uint4(0, 0, 0, 0);
      if constexpr (AFP32) {
        const float* A = (const float*)Ain;
        if (gr < M) {
          const float* p = &A[(size_t)gr * K + k0 + q * 16];
          float4 v0 = *(const float4*)(p + 0), v1 = *(const float4*)(p + 4);
          float4 v2 = *(const float4*)(p + 8), v3 = *(const float4*)(p + 12);
          o0.x = f2bf(v0.x) | (f2bf(v0.y) << 16); o0.y = f2bf(v0.z) | (f2bf(v0.w) << 16);
          o0.z = f2bf(v1.x) | (f2bf(v1.y) << 16); o0.w = f2bf(v1.z) | (f2bf(v1.w) << 16);
          o1.x = f2bf(v2.x) | (f2bf(v2.y) << 16); o1.y = f2bf(v2.z) | (f2bf(v2.w) << 16);
          o1.z = f2bf(v3.x) | (f2bf(v3.y) << 16); o1.w = f2bf(v3.z) | (f2bf(v3.w) << 16);
        }
      } else {
        const unsigned short* A = (const unsigned short*)Ain;
        if (gr < M) {
          const unsigned short* p = &A[(size_t)gr * K + k0 + q * 16];
          o0 = *(const uint4*)(p);
          o1 = *(const uint4*)(p + 8);
        }
      }
      *(uint4*)(AsB + r * 128 + (((unsigned)(q * 32)) ^ swz)) = o0;
      *(uint4*)(AsB + r * 128 + (((unsigned)(q * 32 + 16)) ^ swz)) = o1;
    }
    // ---- stage B from fp32 W[k][n]: BK x BN -> BsB[n][k*2B] bf16 (transposed) ----
    {
      constexpr int N4 = BN / 4;            // float4 chunks per k-row
      constexpr int KPP = 2 * (256 / N4);   // k-rows covered per pass
      int kp = t / N4, n4 = t % N4;
#pragma unroll
      for (int p = 0; p < BK / KPP; ++p) {
        int k = p * KPP + kp * 2;
        float4 va = *(const float4*)&W[(size_t)(k0 + k) * BN + n4 * 4];
        float4 vb = *(const float4*)&W[(size_t)(k0 + k + 1) * BN + n4 * 4];
        float fa[4] = {va.x, va.y, va.z, va.w};
        float fb[4] = {vb.x, vb.y, vb.z, vb.w};
#pragma unroll
        for (int j = 0; j < 4; ++j) {
          int n = n4 * 4 + j;
          unsigned int val = f2bf(fa[j]) | (f2bf(fb[j]) << 16);
          *(unsigned int*)(BsB + n * 128 +
                           (((unsigned)(k * 2)) ^ ((unsigned)((n & 7) << 4)))) = val;
        }
      }
    }
    __syncthreads();
    // ---- MFMA ----
    {
      int ar = wv * 16 + (lane & 15);
      int g = lane >> 4;
      unsigned int aswz = (unsigned int)((ar & 7) << 4);
      unsigned int bswz = (unsigned int)((lane & 7) << 4);
#pragma unroll
      for (int kk = 0; kk < BK; kk += 32) {
        short8v af = *(const short8v*)(AsB + ar * 128 +
                                       (((unsigned)(kk * 2 + g * 16)) ^ aswz));
#pragma unroll
        for (int nt = 0; nt < NT; ++nt) {
          int brr = nt * 16 + (lane & 15);
          short8v bf = *(const short8v*)(BsB + brr * 128 +
                                         (((unsigned)(kk * 2 + g * 16)) ^ bswz));
          acc[nt] = __builtin_amdgcn_mfma_f32_16x16x32_bf16(af, bf, acc[nt], 0, 0, 0);
        }
      }
    }
    __syncthreads();
  }
  // ---- epilogue: D col=lane&15, row=(lane>>4)*4+j ----
  int r0 = m0 + wv * 16 + (lane >> 4) * 4;
  int c0 = lane & 15;
#pragma unroll
  for (int nt = 0; nt < NT; ++nt) {
#pragma unroll
    for (int j = 0; j < 4; ++j) {
      int gr = r0 + j;
      if (gr < M) C[(size_t)gr * BN + nt * 16 + c0] = (unsigned short)f2bf(acc[nt][j]);
    }
  }
}

// ---------------- fused A: edge histogram/rank atomics (blocks < EBLK) ∥ gemm1 ----
__global__ __launch_bounds__(256) void fusedA_kernel(
    const float* __restrict__ x, const float* __restrict__ W1,
    unsigned short* __restrict__ bufA,
    const int* __restrict__ col, const float* __restrict__ ew,
    unsigned long long* __restrict__ packed, unsigned short* __restrict__ rank) {
  if (blockIdx.x < EBLK) {
    int e = blockIdx.x * 256 + threadIdx.x;
    if (e < N_EDGES) {
      int c = col[e];
      unsigned long long fix = (unsigned long long)__float2uint_rn(ew[e] * FIXSCALE);
      unsigned long long old = atomicAdd(&packed[c], (1ULL << 40) | fix);
      rank[e] = (unsigned short)(old >> 40);
    }
    return;
  }
  int m0 = (int)(blockIdx.x - EBLK) * 64;
  gemm_body<N_HID, N_FEAT, true>(x, W1, bufA, N_NODES, m0);
}

// ---------------- layer-2 GEMM ----------------
__global__ __launch_bounds__(256) void gemm2_kernel(
    const unsigned short* __restrict__ bufB, const float* __restrict__ W2,
    unsigned short* __restrict__ bufC) {
  gemm_body<N_CLASS, N_HID, false>(bufB, W2, bufC, N_NODES, (int)blockIdx.x * 64);
}

// ---------------- scan1: unpack counts/dinv + block-local exclusive scan ----------------
__global__ __launch_bounds__(256) void scan1_kernel(
    const unsigned long long* __restrict__ packed, int* __restrict__ rowptr,
    int* __restrict__ partials, float* __restrict__ dinv) {
  __shared__ int wsum[4];
  __shared__ int woff[4];
  int t = threadIdx.x, b = blockIdx.x;
  int base = b * 1024 + t * 4;
  int v0 = 0, v1 = 0, v2 = 0, v3 = 0;
#pragma unroll
  for (int j = 0; j < 4; ++j) {
    int i = base + j;
    if (i < N_NODES) {
      unsigned long long p = packed[i];
      int c = (int)(p >> 40);
      float deg = (float)(long long)(p & 0xFFFFFFFFFFULL) * (1.0f / FIXSCALE);
      dinv[i] = rsqrtf(deg + 1.0f);  // +1 = self-loop weight
      if (j == 0) v0 = c; else if (j == 1) v1 = c; else if (j == 2) v2 = c; else v3 = c;
    }
  }
  int s1 = v0 + v1, s2 = s1 + v2, s3 = s2 + v3;
  int lane = t & 63, w = t >> 6;
  int inc = s3;
#pragma unroll
  for (int off = 1; off < 64; off <<= 1) {
    int u = __shfl_up(inc, off, 64);
    if (lane >= off) inc += u;
  }
  if (lane == 63) wsum[w] = inc;
  __syncthreads();
  if (t == 0) {
    int a = 0;
#pragma unroll
    for (int i = 0; i < 4; ++i) { woff[i] = a; a += wsum[i]; }
    partials[b] = a;
  }
  __syncthreads();
  int ex = woff[w] + inc - s3;
  if (base + 0 < N_NODES) rowptr[base + 0] = ex;
  if (base + 1 < N_NODES) rowptr[base + 1] = ex + v0;
  if (base + 2 < N_NODES) rowptr[base + 2] = ex + s1;
  if (base + 3 < N_NODES) rowptr[base + 3] = ex + s2;
}

__global__ void scan2_kernel(int* __restrict__ partials, int* __restrict__ rowptr) {
  if (threadIdx.x == 0 && blockIdx.x == 0) {
    int a = 0;
    for (int i = 0; i < SCAN_NBLK; ++i) { int x = partials[i]; partials[i] = a; a += x; }
    rowptr[N_NODES] = a;  // == N_EDGES
  }
}

__global__ __launch_bounds__(256) void scan3_kernel(
    int* __restrict__ rowptr, const int* __restrict__ partials) {
  int i = blockIdx.x * 256 + threadIdx.x;
  if (i < N_NODES) rowptr[i] += partials[i >> 10];
}

// ---------------- atomic-free scatter into CSC; packed u32 (row u16 | fp16 norm) ----
__global__ __launch_bounds__(256) void scatter_kernel(
    const int* __restrict__ row, const int* __restrict__ col,
    const float* __restrict__ ew, const unsigned short* __restrict__ rank,
    const float* __restrict__ dinv, const int* __restrict__ rowptr,
    unsigned int* __restrict__ ep, int E) {
  int e = blockIdx.x * 256 + threadIdx.x;
  if (e >= E) return;
  int r = row[e], c = col[e];
  float w = dinv[r] * ew[e] * dinv[c];
  int pos = rowptr[c] + (int)rank[e];
  unsigned int wh = (unsigned int)__half_as_ushort(__float2half(w));
  ep[pos] = (unsigned int)r | (wh << 16);
}

// ---------------- aggregation D=128: 4 gathers in flight; bf16 h in, bf16 out ----
__global__ __launch_bounds__(256) void agg128_kernel(
    const unsigned short* __restrict__ h, const int* __restrict__ rowptr,
    const unsigned int* __restrict__ ep, const float* __restrict__ dinv,
    const float* __restrict__ bias, unsigned short* __restrict__ out, int n) {
  int wid  = (int)((blockIdx.x * 256 + threadIdx.x) >> 6);
  int lane = threadIdx.x & 63;
  if (wid >= n) return;
  int s = rowptr[wid], e_end = rowptr[wid + 1];
  unsigned int f2 = 2u * lane;
  float a0 = 0.f, a1 = 0.f, b0 = 0.f, b1 = 0.f,
        c0 = 0.f, c1 = 0.f, d0 = 0.f, d1 = 0.f;
  int e = s;
  for (; e + 3 < e_end; e += 4) {
    unsigned int p0 = ep[e], p1 = ep[e + 1], p2 = ep[e + 2], p3 = ep[e + 3];
    unsigned int h0 = *(const unsigned int*)(h + ((size_t)(p0 & 0xffffu) << 7) + f2);
    unsigned int h1 = *(const unsigned int*)(h + ((size_t)(p1 & 0xffffu) << 7) + f2);
    unsigned int h2 = *(const unsigned int*)(h + ((size_t)(p2 & 0xffffu) << 7) + f2);
    unsigned int h3 = *(const unsigned int*)(h + ((size_t)(p3 & 0xffffu) << 7) + f2);
    float w0 = __half2float(__ushort_as_half((unsigned short)(p0 >> 16)));
    float w1 = __half2float(__ushort_as_half((unsigned short)(p1 >> 16)));
    float w2 = __half2float(__ushort_as_half((unsigned short)(p2 >> 16)));
    float w3 = __half2float(__ushort_as_half((unsigned short)(p3 >> 16)));
    a0 = fmaf(w0, __uint_as_float(h0 << 16), a0);
    a1 = fmaf(w0, __uint_as_float(h0 & 0xffff0000u), a1);
    b0 = fmaf(w1, __uint_as_float(h1 << 16), b0);
    b1 = fmaf(w1, __uint_as_float(h1 & 0xffff0000u), b1);
    c0 = fmaf(w2, __uint_as_float(h2 << 16), c0);
    c1 = fmaf(w2, __uint_as_float(h2 & 0xffff0000u), c1);
    d0 = fmaf(w3, __uint_as_float(h3 << 16), d0);
    d1 = fmaf(w3, __uint_as_float(h3 & 0xffff0000u), d1);
  }
  for (; e < e_end; ++e) {
    unsigned int p0 = ep[e];
    unsigned int h0 = *(const unsigned int*)(h + ((size_t)(p0 & 0xffffu) << 7) + f2);
    float w0 = __half2float(__ushort_as_half((unsigned short)(p0 >> 16)));
    a0 = fmaf(w0, __uint_as_float(h0 << 16), a0);
    a1 = fmaf(w0, __uint_as_float(h0 & 0xffff0000u), a1);
  }
  float di = dinv[wid], sw = di * di;
  unsigned int hs = *(const unsigned int*)(h + ((size_t)wid << 7) + f2);
  a0 = fmaf(sw, __uint_as_float(hs << 16), a0);
  a1 = fmaf(sw, __uint_as_float(hs & 0xffff0000u), a1);
  float v0 = (a0 + b0) + (c0 + d0) + bias[f2];
  float v1 = (a1 + b1) + (c1 + d1) + bias[f2 + 1];
  v0 = 1.f / (1.f + expf(-v0));
  v1 = 1.f / (1.f + expf(-v1));
  unsigned int o = f2bf(v0) | (f2bf(v1) << 16);
  *(unsigned int*)(out + ((size_t)wid << 7) + f2) = o;
}

// ---------------- aggregation D=64: lane-halves, 4 gathers in flight per half ----
__global__ __launch_bounds__(256) void agg64_kernel(
    const unsigned short* __restrict__ h, const int* __restrict__ rowptr,
    const unsigned int* __restrict__ ep, const float* __restrict__ dinv,
    const float* __restrict__ bias, float* __restrict__ out, int n) {
  int wid  = (int)((blockIdx.x * 256 + threadIdx.x) >> 6);
  int lane = threadIdx.x & 63;
  if (wid >= n) return;
  int half = lane >> 5, ll = lane & 31;
  unsigned int f2 = 2u * ll;
  int s = rowptr[wid], e_end = rowptr[wid + 1];
  float a0 = 0.f, a1 = 0.f, b0 = 0.f, b1 = 0.f,
        c0 = 0.f, c1 = 0.f, d0 = 0.f, d1 = 0.f;
  int e = s + half;
  for (; e + 6 < e_end; e += 8) {
    unsigned int p0 = ep[e], p1 = ep[e + 2], p2 = ep[e + 4], p3 = ep[e + 6];
    unsigned int h0 = *(const unsigned int*)(h + ((size_t)(p0 & 0xffffu) << 6) + f2);
    unsigned int h1 = *(const unsigned int*)(h + ((size_t)(p1 & 0xffffu) << 6) + f2);
    unsigned int h2 = *(const unsigned int*)(h + ((size_t)(p2 & 0xffffu) << 6) + f2);
    unsigned int h3 = *(const unsigned int*)(h + ((size_t)(p3 & 0xffffu) << 6) + f2);
    float w0 = __half2float(__ushort_as_half((unsigned short)(p0 >> 16)));
    float w1 = __half2float(__ushort_as_half((unsigned short)(p1 >> 16)));
    float w2 = __half2float(__ushort_as_half((unsigned short)(p2 >> 16)));
    float w3 = __half2float(__ushort_as_half((unsigned short)(p3 >> 16)));
    a0 = fmaf(w0, __uint_as_float(h0 << 16), a0);
    a1 = fmaf(w0, __uint_as_float(h0 & 0xffff0000u), a1);
    b0 = fmaf(w1, __uint_as_float(h1 << 16), b0);
    b1 = fmaf(w1, __uint_as_float(h1 & 0xffff0000u), b1);
    c0 = fmaf(w2, __uint_as_float(h2 << 16), c0);
    c1 = fmaf(w2, __uint_as_float(h2 & 0xffff0000u), c1);
    d0 = fmaf(w3, __uint_as_float(h3 << 16), d0);
    d1 = fmaf(w3, __uint_as_float(h3 & 0xffff0000u), d1);
  }
  for (; e < e_end; e += 2) {
    unsigned int p0 = ep[e];
    unsigned int h0 = *(const unsigned int*)(h + ((size_t)(p0 & 0xffffu) << 6) + f2);
    float w0 = __half2float(__ushort_as_half((unsigned short)(p0 >> 16)));
    a0 = fmaf(w0, __uint_as_float(h0 << 16), a0);
    a1 = fmaf(w0, __uint_as_float(h0 & 0xffff0000u), a1);
  }
  a0 = (a0 + b0) + (c0 + d0);
  a1 = (a1 + b1) + (c1 + d1);
  if (half == 0) {  // self-loop term exactly once
    float di = dinv[wid], sw = di * di;
    unsigned int hs = *(const unsigned int*)(h + ((size_t)wid << 6) + f2);
    a0 = fmaf(sw, __uint_as_float(hs << 16), a0);
    a1 = fmaf(sw, __uint_as_float(hs & 0xffff0000u), a1);
  }
  a0 += __shfl_xor(a0, 32, 64);
  a1 += __shfl_xor(a1, 32, 64);
  if (half == 0) {
    float v0 = tanhf(a0 + bias[f2]);
    float v1 = tanhf(a1 + bias[f2 + 1]);
    *(float2*)&out[(size_t)wid * 64 + f2] = make_float2(v0, v1);
  }
}

extern "C" void kernel_launch(void* const* d_in, const int* in_sizes, int n_in,
                              void* d_out, int out_size, void* d_ws, size_t ws_size,
                              hipStream_t stream) {
  const float* x  = (const float*)d_in[0];
  const int*   ei = (const int*)d_in[1];
  const float* ew = (const float*)d_in[2];
  const float* W1 = (const float*)d_in[3];
  const float* b1 = (const float*)d_in[4];
  const float* W2 = (const float*)d_in[5];
  const float* b2 = (const float*)d_in[6];
  float* out = (float*)d_out;

  const int* row = ei;            // edge_index[0]
  const int* col = ei + N_EDGES;  // edge_index[1]

  char* ws = (char*)d_ws;
  size_t off = 0;
  auto alloc = [&](size_t bytes) {
    void* p = ws + off;
    off = (off + bytes + 255) & ~(size_t)255;
    return p;
  };
  unsigned long long* packed = (unsigned long long*)alloc(N_NODES * 8);
  int*   rowptr   = (int*)alloc((N_NODES + 1) * 4);
  float* dinv     = (float*)alloc(N_NODES * 4);
  int*   partials = (int*)alloc(SCAN_NBLK * 4);
  unsigned short* rank = (unsigned short*)alloc((size_t)N_EDGES * 2);
  unsigned int* ep = (unsigned int*)alloc((size_t)N_EDGES * 4);
  unsigned short* bufA = (unsigned short*)alloc((size_t)N_NODES * N_HID * 2);   // bf16 x@W1
  unsigned short* bufB = (unsigned short*)alloc((size_t)N_NODES * N_HID * 2);   // bf16 h1
  unsigned short* bufC = (unsigned short*)alloc((size_t)N_NODES * N_CLASS * 2); // bf16 h1@W2

  hipMemsetAsync(packed, 0, N_NODES * 8, stream);

  int eblocks = EBLK;
  int nblocks = (N_NODES + 255) / 256;

  // [edge atomics ∥ layer-1 GEMM] in one launch (block-specialized)
  fusedA_kernel<<<EBLK + GBLK, 256, 0, stream>>>(x, W1, bufA, col, ew, packed, rank);

  scan1_kernel<<<SCAN_NBLK, 256, 0, stream>>>(packed, rowptr, partials, dinv);
  scan2_kernel<<<1, 64, 0, stream>>>(partials, rowptr);
  scan3_kernel<<<nblocks, 256, 0, stream>>>(rowptr, partials);
  scatter_kernel<<<eblocks, 256, 0, stream>>>(row, col, ew, rank, dinv, rowptr, ep, N_EDGES);

  // layer 1 aggregate: h1 = sigmoid(A @ bufA + b1)
  agg128_kernel<<<(N_NODES * 64 + 255) / 256, 256, 0, stream>>>(
      bufA, rowptr, ep, dinv, b1, bufB, N_NODES);

  // layer 2: out = tanh(A @ (h1 @ W2) + b2)
  gemm2_kernel<<<GBLK, 256, 0, stream>>>(bufB, W2, bufC);
  agg64_kernel<<<(N_NODES * 64 + 255) / 256, 256, 0, stream>>>(
      bufC, rowptr, ep, dinv, b2, out, N_NODES);
}